// Round 7
// baseline (65.365 us; speedup 1.0000x reference)
//
#include <hip/hip_runtime.h>

#define DZ 512
#define DT 66048
#define NT 4128  // 16-col output tiles
#define SV_JITTER 1e-4f

typedef __attribute__((ext_vector_type(8))) short bf8;
typedef __attribute__((ext_vector_type(4))) float f4;

typedef __attribute__((address_space(1))) const void glb_t;
typedef __attribute__((address_space(3))) void lds_t;

__device__ __forceinline__ short f2bf(float f) {
  unsigned u = __builtin_bit_cast(unsigned, f);
  return (short)((u + 0x7FFFu + ((u >> 16) & 1u)) >> 16);
}

__device__ __forceinline__ bf8 cvt8(float4 a, float4 b) {
  bf8 r = { f2bf(a.x), f2bf(a.y), f2bf(a.z), f2bf(a.w),
            f2bf(b.x), f2bf(b.y), f2bf(b.z), f2bf(b.w) };
  return r;
}

// tril/jitter cvt: element t has k-index kbase+t
__device__ __forceinline__ bf8 cvt8_tril(float4 x, float4 y, int kbase, int diag) {
  float v[8] = {x.x, x.y, x.z, x.w, y.x, y.y, y.z, y.w};
  bf8 r;
  #pragma unroll
  for (int t = 0; t < 8; ++t) {
    int k = kbase + t;
    float val = (k < diag) ? v[t] : ((k == diag) ? v[t] + SV_JITTER : 0.f);
    r[t] = f2bf(val);
  }
  return r;
}

// One 16-col tile, all 128 samples (8 M-frags). B read once chip-wide.
// acc layout per mfma_f32_16x16x32_bf16: col=lane&15, row=4*(lane>>4)+reg.
template <bool IS_Z>
__device__ __forceinline__ void process_tile(
    int col0, int lcol, int q, int lane, const short* __restrict__ Afrag,
    float* __restrict__ dump,
    const float* __restrict__ mv, const float* __restrict__ Lz,
    const float* __restrict__ Ly, const float* __restrict__ Lyz,
    const float* __restrict__ eps, float* __restrict__ out) {
  const int colL = col0 + lcol;
  const float* bptr = IS_Z ? (Lz + (size_t)colL * DZ)
                           : (Lyz + (size_t)(colL - DZ) * DZ);
  const int bdiag = colL;  // tril diag (IS_Z only)

  // --- DRAM-burst prefetch: the tile's B panel (16 rows x 2KB = contiguous
  // 32KB) streamed in pure address order into a scratch LDS dump via
  // global_load_lds (no dest VGPRs, no value waits, result never read).
  // Fragment loads below MSHR-merge onto these in-flight lines.
  if (!IS_Z) {
    const float* panel = Lyz + (size_t)(col0 - DZ) * DZ;
    #pragma unroll
    for (int i = 0; i < 32; ++i) {
      __builtin_amdgcn_global_load_lds((glb_t*)(panel + i * 256 + lane * 4),
                                       (lds_t*)dump, 16, 0, 0);
    }
    __builtin_amdgcn_sched_barrier(0);  // keep prefetch ahead of the pipeline
  }

  f4 acc[8];
  #pragma unroll
  for (int mi = 0; mi < 8; ++mi) acc[mi] = f4{0.f, 0.f, 0.f, 0.f};

  float4 bx0, by0, bx1, by1, bx2, by2, bx3, by3;
  bf8 a[8];  // single A buffer (keeps VGPR under the 4-wave/SIMD cap)

  auto loadB = [&](int kk, float4& x, float4& y) {
    const float* p = bptr + kk * 32 + 8 * q;
    x = *(const float4*)p;
    y = *(const float4*)(p + 4);
  };
  auto loadA = [&](int kk) {
    #pragma unroll
    for (int mi = 0; mi < 8; ++mi)
      a[mi] = *(const bf8*)&Afrag[(kk * 8 + mi) * 512 + lane * 8];
  };
  auto mk = [&](float4 x, float4 y, int kb) {
    return IS_Z ? cvt8_tril(x, y, kb, bdiag) : cvt8(x, y);
  };
  auto domfma = [&](bf8 bf) {
    #pragma unroll
    for (int mi = 0; mi < 8; ++mi)
      acc[mi] = __builtin_amdgcn_mfma_f32_16x16x32_bf16(a[mi], bf, acc[mi], 0, 0, 0);
  };

  // prologue: B 4-deep in flight
  loadB(0, bx0, by0); loadB(1, bx1, by1);
  loadB(2, bx2, by2); loadB(3, bx3, by3);

  int kk = 0;
  #pragma unroll 1
  for (int kt = 0; kt < 3; ++kt, kk += 4) {  // steps 0..11; refills all < 16
    { loadA(kk);
      bf8 bf = mk(bx0, by0, kk * 32 + 8 * q);
      loadB(kk + 4, bx0, by0); domfma(bf); }
    { loadA(kk + 1);
      bf8 bf = mk(bx1, by1, (kk + 1) * 32 + 8 * q);
      loadB(kk + 5, bx1, by1); domfma(bf); }
    { loadA(kk + 2);
      bf8 bf = mk(bx2, by2, (kk + 2) * 32 + 8 * q);
      loadB(kk + 6, bx2, by2); domfma(bf); }
    { loadA(kk + 3);
      bf8 bf = mk(bx3, by3, (kk + 3) * 32 + 8 * q);
      loadB(kk + 7, bx3, by3); domfma(bf); }
  }

  // diag-step B prefetch (y tiles): in flight across the peeled steps
  float4 dbx{}, dby{};
  int nb = 0, dI = 0;
  if (!IS_Z) {
    nb = (col0 - DZ) >> 5;            // 32x32 Ly block
    dI = (col0 - DZ) & 31;            // tile's base row within block (0 or 16)
    const float* pb = Ly + ((size_t)nb * 32 + dI + lcol) * 32 + 8 * q;
    dbx = *(const float4*)pb; dby = *(const float4*)(pb + 4);
  }

  // peeled steps 12..15 (buffers hold exactly 12,13,14,15)
  { loadA(12); bf8 bf = mk(bx0, by0, 12 * 32 + 8 * q); domfma(bf); }
  { loadA(13); bf8 bf = mk(bx1, by1, 13 * 32 + 8 * q); domfma(bf); }
  { loadA(14); bf8 bf = mk(bx2, by2, 14 * 32 + 8 * q); domfma(bf); }
  { loadA(15); bf8 bf = mk(bx3, by3, 15 * 32 + 8 * q); domfma(bf); }

  // block-diag einsum step (y tiles): A from global (eps_y cols not staged)
  if (!IS_Z) {
    const bf8 dbf = cvt8_tril(dbx, dby, 8 * q, dI + lcol);
    const float* abase = eps + (size_t)lcol * DT + DZ + nb * 32 + 8 * q;
    float4 rx[4], ry[4];
    #pragma unroll
    for (int mi = 0; mi < 4; ++mi) {  // batch 1: rows 0..63
      const float* pa = abase + (size_t)mi * 16 * DT;
      rx[mi] = *(const float4*)pa; ry[mi] = *(const float4*)(pa + 4);
    }
    #pragma unroll
    for (int mi = 0; mi < 4; ++mi) {
      bf8 af = cvt8(rx[mi], ry[mi]);
      acc[mi] = __builtin_amdgcn_mfma_f32_16x16x32_bf16(af, dbf, acc[mi], 0, 0, 0);
    }
    #pragma unroll
    for (int mi = 0; mi < 4; ++mi) {  // batch 2: rows 64..127
      const float* pa = abase + (size_t)(mi + 4) * 16 * DT;
      rx[mi] = *(const float4*)pa; ry[mi] = *(const float4*)(pa + 4);
    }
    #pragma unroll
    for (int mi = 0; mi < 4; ++mi) {
      bf8 af = cvt8(rx[mi], ry[mi]);
      acc[mi + 4] = __builtin_amdgcn_mfma_f32_16x16x32_bf16(af, dbf, acc[mi + 4], 0, 0, 0);
    }
  }

  const float mval = mv[colL];
  #pragma unroll
  for (int mi = 0; mi < 8; ++mi) {
    #pragma unroll
    for (int r = 0; r < 4; ++r) {
      out[(size_t)(16 * mi + 4 * q + r) * DT + colL] = acc[mi][r] + mval;
    }
  }
}

// 256 blocks (1/CU) x 1024 threads (16 waves = 4/SIMD). Stage ALL of eps_z
// into LDS in MFMA-frag layout once; then each wave independently processes
// ONE 16-col tile (T = b*16 + wv), zero barriers after staging. Wave 15 of
// blocks 0..31 takes one extra tile (4096+b).
__global__ __launch_bounds__(1024, 4)
void sv_kernel(const float* __restrict__ mv, const float* __restrict__ Lz,
               const float* __restrict__ Ly, const float* __restrict__ Lyz,
               const float* __restrict__ eps, float* __restrict__ out) {
  // region r = kk*8+mi: slot==lane holds eps[16*mi+(lane&15)][kk*32+(lane>>4)*8..+7]
  __shared__ short Afrag[128 * 512];  // 128 KB
  __shared__ float dump[256];         // 1 KB prefetch dump (write-only, racy by design)

  const int tid = threadIdx.x;
  const int lane = tid & 63;
  const int wv = tid >> 6;
  const int lcol = lane & 15;
  const int q = lane >> 4;

  {  // stage eps_z once: wave-uniform region, slot=lane -> linear ds_write
    const int slot = lane;
    const int r0 = wv * 8;
    #pragma unroll 4
    for (int i = 0; i < 8; ++i) {
      const int r = r0 + i;  // 0..127; mi=r&7, kk=r>>3
      const float* p = eps + (size_t)(16 * (r & 7) + (slot & 15)) * DT +
                       (r >> 3) * 32 + (slot >> 4) * 8;
      float4 x = *(const float4*)p;
      float4 y = *(const float4*)(p + 4);
      *(bf8*)&Afrag[r * 512 + slot * 8] = cvt8(x, y);
    }
  }
  __syncthreads();  // the ONLY barrier

  {
    const int T = blockIdx.x * 16 + wv;  // 0..4095
    const int col0 = T * 16;
    if (col0 < DZ)
      process_tile<true>(col0, lcol, q, lane, Afrag, dump, mv, Lz, Ly, Lyz, eps, out);
    else
      process_tile<false>(col0, lcol, q, lane, Afrag, dump, mv, Lz, Ly, Lyz, eps, out);
  }
  if (wv == 15 && blockIdx.x < 32) {  // leftover tiles 4096..4127 (all y)
    const int col0 = (4096 + blockIdx.x) * 16;
    process_tile<false>(col0, lcol, q, lane, Afrag, dump, mv, Lz, Ly, Lyz, eps, out);
  }
}

extern "C" void kernel_launch(void* const* d_in, const int* in_sizes, int n_in,
                              void* d_out, int out_size, void* d_ws, size_t ws_size,
                              hipStream_t stream) {
  const float* m   = (const float*)d_in[0];
  const float* Lz  = (const float*)d_in[1];
  const float* Ly  = (const float*)d_in[2];
  const float* Lyz = (const float*)d_in[3];
  const float* eps = (const float*)d_in[4];
  float* out = (float*)d_out;
  sv_kernel<<<dim3(256), dim3(1024), 0, stream>>>(m, Lz, Ly, Lyz, eps, out);
}